// Round 12
// baseline (1846.648 us; speedup 1.0000x reference)
//
#include <hip/hip_runtime.h>

#define D_IN   2048
#define WIDTH  16384
#define BATCH  8192
#define TOPK   64

// ---- K1 (MFMA GEMM, m97 structure + T2 swizzle) ----
#define BM  128
#define BN  128
#define BK  64

// ---- K2a (select) ----
#define CAP   256
#define COLL  0.022f      // collect band on bf16-staged s'
#define SURE  0.018f      // certainty band on f32-staged s

typedef unsigned int   u32;
typedef unsigned short u16;
typedef __attribute__((ext_vector_type(8))) short short8;
typedef __attribute__((ext_vector_type(4))) float f32x4;

__device__ __forceinline__ u32 rne16(float f) {           // f32 -> bf16 bits (RNE)
  u32 u = __float_as_uint(f);
  return (u + 0x7FFFu + ((u >> 16) & 1u)) >> 16;
}
__device__ __forceinline__ float bf16f(u16 h) {
  return __uint_as_float(((u32)h) << 16);
}
__device__ __forceinline__ void gload_lds16(const void* g, void* l) {
  __builtin_amdgcn_global_load_lds(
      (__attribute__((address_space(1))) void*)g,
      (__attribute__((address_space(3))) void*)l, 16, 0, 0);
}

// =============== P0: f32 -> bf16 (RNE) bulk convert into workspace ===============
__global__ __launch_bounds__(256) void cvt_bf16_k(
    const float* __restrict__ in, u16* __restrict__ out, int n4)
{
  int stride = gridDim.x * 256;
  for (int i = blockIdx.x * 256 + threadIdx.x; i < n4; i += stride) {
    float4 v = ((const float4*)in)[i];
    ((uint2*)out)[i] = make_uint2(rne16(v.x) | (rne16(v.y) << 16),
                                  rne16(v.z) | (rne16(v.w) << 16));
  }
}

// ====== K1: z = relu(x @ W^T + b_enc), bf16 MFMA, gload_lds + XOR swizzle ======
// Block order: bn fast within bm (round-10 order). All XCDs sweep the same A
// panel concurrently; W streams through L3 once per sweep (FETCH ~750 MB).
// LDS swizzle (rule #21, both sides): staging pre-swizzles the per-lane global
// k-granule ((lane&7)^(lane>>3))*16B; reads apply ko ^= (row&7)<<3 (elems).
__global__ __launch_bounds__(256) void sae_enc_mfma4(
    const u16* __restrict__ xbf, const u16* __restrict__ wbf,
    const float* __restrict__ b_enc, float* __restrict__ z)
{
  __shared__ u16 As[BM * BK];      // 16384 B
  __shared__ u16 Bs[BN * BK];      // 16384 B

  const int tid  = threadIdx.x;
  const int lane = tid & 63;
  const int w    = tid >> 6;
  const int wm   = w >> 1;
  const int wn   = w & 1;
  const int bn   = blockIdx.x;     // fast
  const int bm   = blockIdx.y;     // slow

  f32x4 acc[4][4];
#pragma unroll
  for (int i = 0; i < 4; i++)
#pragma unroll
    for (int j = 0; j < 4; j++) acc[i][j] = (f32x4){0.f, 0.f, 0.f, 0.f};

  const u16* ag = xbf + (size_t)(bm * BM) * D_IN;
  const u16* bg = wbf + (size_t)(bn * BN) * D_IN;

  const int rL    = lane >> 3;                          // row within 8-row chunk
  const int kq_sw = ((lane & 7) ^ (lane >> 3)) * 8;     // pre-swizzled k offset (elems)

  for (int k0 = 0; k0 < D_IN; k0 += BK) {
    __syncthreads();
#pragma unroll
    for (int c = 0; c < 4; c++) {
      int r0 = (w * 4 + c) * 8;
      gload_lds16(ag + (size_t)(r0 + rL) * D_IN + k0 + kq_sw, &As[r0 * BK]);
    }
#pragma unroll
    for (int c = 0; c < 4; c++) {
      int r0 = (w * 4 + c) * 8;
      gload_lds16(bg + (size_t)(r0 + rL) * D_IN + k0 + kq_sw, &Bs[r0 * BK]);
    }
    __syncthreads();
#pragma unroll
    for (int kf = 0; kf < 2; kf++) {
      int ko = kf * 32 + (lane >> 4) * 8;
      short8 af[4], bf[4];
#pragma unroll
      for (int mi = 0; mi < 4; mi++) {
        int row = wm * 64 + mi * 16 + (lane & 15);
        af[mi] = *(const short8*)&As[row * BK + (ko ^ ((row & 7) << 3))];
      }
#pragma unroll
      for (int ni = 0; ni < 4; ni++) {
        int row = wn * 64 + ni * 16 + (lane & 15);
        bf[ni] = *(const short8*)&Bs[row * BK + (ko ^ ((row & 7) << 3))];
      }
#pragma unroll
      for (int mi = 0; mi < 4; mi++)
#pragma unroll
        for (int ni = 0; ni < 4; ni++)
          acc[mi][ni] = __builtin_amdgcn_mfma_f32_16x16x32_bf16(
              af[mi], bf[ni], acc[mi][ni], 0, 0, 0);
    }
  }

  // epilogue: C layout col = lane&15, row = (lane>>4)*4 + reg
  int colbase = bn * BN + wn * 64 + (lane & 15);
  int rowbase = bm * BM + wm * 64 + (lane >> 4) * 4;
#pragma unroll
  for (int ni = 0; ni < 4; ni++) {
    int col = colbase + ni * 16;
    float be = b_enc[col];
#pragma unroll
    for (int mi = 0; mi < 4; mi++) {
#pragma unroll
      for (int r = 0; r < 4; r++) {
        int row = rowbase + mi * 16 + r;
        float v = acc[mi][ni][r] + be;
        z[(size_t)row * WIDTH + col] = v > 0.f ? v : 0.f;
      }
    }
  }
}

// ========= K2a: per-row top-64 set selection (register-resident row) =========
__global__ __launch_bounds__(256) void sae_select2(
    float* __restrict__ z, const float* __restrict__ x,
    const float* __restrict__ W, const float* __restrict__ b_enc,
    float* __restrict__ xhat)
{
  __shared__ float  xrow[D_IN];
  __shared__ u32    hist[256];
  __shared__ int    ci[CAP];
  __shared__ float  cs[CAP];
  __shared__ int    ucand[CAP];
  __shared__ double uval[CAP];
  __shared__ u32    wflag[CAP];
  __shared__ int    si[TOPK];
  __shared__ float  sv[TOPK];
  __shared__ int    ncand_s, nunc_s, m_s, sel_hi_s;
  __shared__ u32    g1_s;
  __shared__ float  tp_s;

  const int tid = threadIdx.x;
  const int b   = blockIdx.x;
  float* zrow = z + (size_t)b * WIDTH;
  const float4* zr4 = (const float4*)zrow;

  for (int i = tid; i < D_IN / 4; i += 256)
    ((float4*)xrow)[i] = ((const float4*)(x + (size_t)b * D_IN))[i];
  if (tid == 0) { ncand_s = 0; nunc_s = 0; m_s = 0; }
  if (tid < TOPK) { si[tid] = 0; sv[tid] = 0.f; }
  hist[tid] = 0;
  __syncthreads();

  // one z read: row lives in 32 packed-bf16 registers per thread
  u32 pk[32];
#pragma unroll
  for (int i = 0; i < 16; i++) {
    float4 v = zr4[i * 256 + tid];
    pk[2 * i]     = rne16(v.x) | (rne16(v.y) << 16);
    pk[2 * i + 1] = rne16(v.z) | (rne16(v.w) << 16);
  }

  // radix pass 1 on bf16 bits (nonneg -> order-preserving)
#pragma unroll
  for (int i = 0; i < 32; i++) {
    u32 p = pk[i];
    atomicAdd(&hist[(p >> 8) & 255u], 1u);
    atomicAdd(&hist[p >> 24], 1u);
  }
  __syncthreads();
  if (tid == 0) {
    u32 cum = 0; int hi = 255;
    for (; hi > 0; hi--) { if (cum + hist[hi] >= TOPK) break; cum += hist[hi]; }
    sel_hi_s = hi; g1_s = cum;
  }
  __syncthreads();
  int sel_hi = sel_hi_s;
  hist[tid] = 0;
  __syncthreads();
#pragma unroll
  for (int i = 0; i < 32; i++) {
    u32 p = pk[i];
    if ((int)((p >> 8) & 255u) == sel_hi) atomicAdd(&hist[p & 255u], 1u);
    if ((int)(p >> 24) == sel_hi) atomicAdd(&hist[(p >> 16) & 255u], 1u);
  }
  __syncthreads();
  if (tid == 0) {
    u32 target = TOPK - g1_s;
    u32 cum = 0; int lo = 255;
    for (; lo > 0; lo--) { cum += hist[lo]; if (cum >= target) break; }
    tp_s = bf16f((u16)((sel_hi << 8) | lo));
  }
  __syncthreads();
  float tp = tp_s;
  float cLo = tp - COLL;

  // collect candidates from registers
#pragma unroll
  for (int i = 0; i < 16; i++) {
    u32 p0 = pk[2 * i], p1 = pk[2 * i + 1];
    int j0 = (i * 256 + tid) * 4;
    if (bf16f((u16)p0) >= cLo)         { int p = atomicAdd(&ncand_s, 1); if (p < CAP) ci[p] = j0; }
    if (bf16f((u16)(p0 >> 16)) >= cLo) { int p = atomicAdd(&ncand_s, 1); if (p < CAP) ci[p] = j0 + 1; }
    if (bf16f((u16)p1) >= cLo)         { int p = atomicAdd(&ncand_s, 1); if (p < CAP) ci[p] = j0 + 2; }
    if (bf16f((u16)(p1 >> 16)) >= cLo) { int p = atomicAdd(&ncand_s, 1); if (p < CAP) ci[p] = j0 + 3; }
  }
  __syncthreads();
  int nc = ncand_s; if (nc > CAP) nc = CAP;

  // classify with the f32 staged value: sure-in / uncertain / out
  for (int c = tid; c < nc; c += 256) {
    float s = zrow[ci[c]];
    cs[c] = s;
    if (s > tp + SURE) { atomicAdd(&m_s, 1); wflag[c] = 1u; }
    else {
      wflag[c] = 0u;
      if (s >= tp - SURE) { int q = atomicAdd(&nunc_s, 1); ucand[q] = c; }
    }
  }
  __syncthreads();
  int m = m_s, nu = nunc_s;
  int k_rem = TOPK - m;

  // f64-exact recompute of uncertain only (f32 W: matches np reference exactly)
  int wv = tid >> 6, lane = tid & 63;
  for (int q = wv; q < nu; q += 4) {
    int jc = ci[ucand[q]];
    const float4* wr = (const float4*)(W + (size_t)jc * D_IN);
    double s = 0.0;
    for (int it = 0; it < D_IN / 4 / 64; it++) {
      float4 wd = wr[it * 64 + lane];
      int d = (it * 64 + lane) * 4;
      s += (double)xrow[d + 0] * (double)wd.x;
      s += (double)xrow[d + 1] * (double)wd.y;
      s += (double)xrow[d + 2] * (double)wd.z;
      s += (double)xrow[d + 3] * (double)wd.w;
    }
    for (int off = 32; off >= 1; off >>= 1) s += __shfl_down(s, off, 64);
    if (lane == 0) {
      double v = s + (double)b_enc[jc];
      uval[q] = v > 0.0 ? v : 0.0;
    }
  }
  __syncthreads();

  // rank uncertain (desc, lower index ties -> matches lax.top_k); take k_rem
  for (int q = tid; q < nu; q += 256) {
    double v = uval[q]; int jq = ci[ucand[q]];
    int rank = 0;
    for (int p = 0; p < nu; p++) {
      double vp = uval[p];
      if (vp > v || (vp == v && ci[ucand[p]] < jq)) rank++;
    }
    if (rank < k_rem) wflag[ucand[q]] = 1u;
  }
  __syncthreads();

  // deterministic slots: winners ordered by feature index
  for (int c = tid; c < nc; c += 256) {
    if (wflag[c]) {
      int jme = ci[c];
      int slot = 0;
      for (int p = 0; p < nc; p++) slot += (wflag[p] && ci[p] < jme) ? 1 : 0;
      si[slot] = jme;
      sv[slot] = cs[c];
    }
  }
  __syncthreads();

  // zero the z row, scatter the 64 winners (staged f32 values)
  for (int i = tid; i < WIDTH / 4; i += 256)
    *(float4*)(zrow + i * 4) = make_float4(0.f, 0.f, 0.f, 0.f);
  __syncthreads();
  if (tid < TOPK) zrow[si[tid]] = sv[tid];

  // stash compact list in the xhat row this block's decode will overwrite
  u32* lidx = (u32*)(xhat + (size_t)b * D_IN);
  if (tid < TOPK) {
    lidx[tid] = (u32)si[tid];
    ((float*)lidx)[TOPK + tid] = sv[tid];
  }
}

// ========= K2b: sparse decode from bf16 W (half traffic, cache-hot) =========
__global__ __launch_bounds__(256) void sae_decode2(
    const u16* __restrict__ wbf, const float* __restrict__ b_dec,
    float* __restrict__ xhat)
{
  __shared__ int   si[TOPK];
  __shared__ float sv[TOPK];
  const int tid = threadIdx.x;
  const int b   = blockIdx.x;
  float* xo = xhat + (size_t)b * D_IN;

  if (tid < TOPK) {
    si[tid] = (int)((const u32*)xo)[tid];
    sv[tid] = xo[TOPK + tid];
  }
  __syncthreads();

  float a[8];
#pragma unroll
  for (int u = 0; u < 8; u++) a[u] = 0.f;
  for (int k = 0; k < TOPK; k++) {
    int j = si[k]; float v = sv[k];
    uint4 wv = *(const uint4*)(wbf + (size_t)j * D_IN + tid * 8);   // 8 bf16, coalesced
    a[0] = fmaf(v, __uint_as_float(wv.x << 16),        a[0]);
    a[1] = fmaf(v, __uint_as_float(wv.x & 0xFFFF0000u), a[1]);
    a[2] = fmaf(v, __uint_as_float(wv.y << 16),        a[2]);
    a[3] = fmaf(v, __uint_as_float(wv.y & 0xFFFF0000u), a[3]);
    a[4] = fmaf(v, __uint_as_float(wv.z << 16),        a[4]);
    a[5] = fmaf(v, __uint_as_float(wv.z & 0xFFFF0000u), a[5]);
    a[6] = fmaf(v, __uint_as_float(wv.w << 16),        a[6]);
    a[7] = fmaf(v, __uint_as_float(wv.w & 0xFFFF0000u), a[7]);
  }
  int d0 = tid * 8;
  float4 bd0 = *(const float4*)(b_dec + d0);
  float4 bd1 = *(const float4*)(b_dec + d0 + 4);
  __syncthreads();   // stash reads done before overwrite
  *(float4*)(xo + d0)     = make_float4(a[0] + bd0.x, a[1] + bd0.y, a[2] + bd0.z, a[3] + bd0.w);
  *(float4*)(xo + d0 + 4) = make_float4(a[4] + bd1.x, a[5] + bd1.y, a[6] + bd1.z, a[7] + bd1.w);
}

// ------------------------------- launch -------------------------------
extern "C" void kernel_launch(void* const* d_in, const int* in_sizes, int n_in,
                              void* d_out, int out_size, void* d_ws, size_t ws_size,
                              hipStream_t stream) {
  const float* x     = (const float*)d_in[0];
  const float* W     = (const float*)d_in[1];
  const float* b_enc = (const float*)d_in[2];
  const float* b_dec = (const float*)d_in[3];
  (void)in_sizes; (void)n_in; (void)out_size; (void)ws_size;

  float* z_out = (float*)d_out;                      // [BATCH][WIDTH] f32
  float* xhat  = z_out + (size_t)BATCH * WIDTH;      // [BATCH][D_IN] f32

  u16* xbf = (u16*)d_ws;                             // 33.5 MB
  u16* wbf = xbf + (size_t)BATCH * D_IN;             // 67.1 MB

  cvt_bf16_k<<<2048, 256, 0, stream>>>(x, xbf, BATCH * D_IN / 4);
  cvt_bf16_k<<<2048, 256, 0, stream>>>(W, wbf, WIDTH * D_IN / 4);

  dim3 g1(WIDTH / BN, BATCH / BM);                   // bn fast, bm slow
  sae_enc_mfma4<<<g1, 256, 0, stream>>>(xbf, wbf, b_enc, z_out);
  sae_select2<<<BATCH, 256, 0, stream>>>(z_out, x, W, b_enc, xhat);
  sae_decode2<<<BATCH, 256, 0, stream>>>(wbf, b_dec, xhat);
}

// Round 13
// 1741.720 us; speedup vs baseline: 1.0602x; 1.0602x over previous
//
#include <hip/hip_runtime.h>

#define D_IN   2048
#define WIDTH  16384
#define BATCH  8192
#define TOPK   64
#define NT     (D_IN / 64)     // 32 K-tiles

// ---- K2a (select) ----
#define CAP   256
#define COLL  0.022f
#define SURE  0.018f

typedef unsigned int   u32;
typedef unsigned short u16;
typedef __attribute__((ext_vector_type(8))) short short8;
typedef __attribute__((ext_vector_type(4))) float f32x4;

__device__ __forceinline__ u32 rne16(float f) {
  u32 u = __float_as_uint(f);
  return (u + 0x7FFFu + ((u >> 16) & 1u)) >> 16;
}
__device__ __forceinline__ float bf16f(u16 h) {
  return __uint_as_float(((u32)h) << 16);
}
__device__ __forceinline__ void gload_lds16(const void* g, void* l) {
  __builtin_amdgcn_global_load_lds(
      (__attribute__((address_space(1))) void*)g,
      (__attribute__((address_space(3))) void*)l, 16, 0, 0);
}

// =============== P0: f32 -> bf16 (RNE) bulk convert into workspace ===============
__global__ __launch_bounds__(256) void cvt_bf16_k(
    const float* __restrict__ in, u16* __restrict__ out, int n4)
{
  int stride = gridDim.x * 256;
  for (int i = blockIdx.x * 256 + threadIdx.x; i < n4; i += stride) {
    float4 v = ((const float4*)in)[i];
    ((uint2*)out)[i] = make_uint2(rne16(v.x) | (rne16(v.y) << 16),
                                  rne16(v.z) | (rne16(v.w) << 16));
  }
}

// ====== K1: 256x256 8-phase counted-vmcnt MFMA GEMM ======
// LDS map (128 KiB): A: [2buf][256 row][8 gran x16B] @0 (64KB)
//                    B: [2buf][2 kf][256 row][4 gran x16B] @65536 (64KB)
// Swizzle: LDS granule g holds global granule g^(row&7) (A) / g^(row&3) (B);
// staging pre-swizzles the per-lane GLOBAL source (gload_lds writes linearly).
// Staging for tile T+1 during T: P0:A0(rows0-127) P1:Bkf0 P2:A1 P3:Bkf1.
// Waits: vmcnt(4) at P1-close (retires Bkf1 of T, needed P2);
//        vmcnt(2) at P3-close (retires A0,Bkf0,A1 of T+1, needed next P0).
// Never drains to 0; 2-8 loads always in flight.
#define MFMA16(MIH)                                                          \
  _Pragma("unroll")                                                          \
  for (int i_ = 0; i_ < 4; i_++)                                             \
    _Pragma("unroll")                                                        \
    for (int n_ = 0; n_ < 4; n_++)                                           \
      acc[(MIH) * 4 + i_][n_] = __builtin_amdgcn_mfma_f32_16x16x32_bf16(     \
          af[i_], bfr[n_], acc[(MIH) * 4 + i_][n_], 0, 0, 0);

__global__ __launch_bounds__(512, 2) void sae_enc_8ph(
    const u16* __restrict__ xbf, const u16* __restrict__ wbf,
    const float* __restrict__ b_enc, float* __restrict__ z)
{
  __shared__ char smem[131072];

  const int tid  = threadIdx.x;
  const int lane = tid & 63;
  const int w    = tid >> 6;      // 0..7
  const int wm   = w >> 2;        // 0..1
  const int wn   = w & 3;         // 0..3
  const int bn   = blockIdx.x;    // fast: all XCDs share the same A panel sweep
  const int bm   = blockIdx.y;
  const int l15  = lane & 15, l4 = lane >> 4;

  f32x4 acc[8][4];
#pragma unroll
  for (int i = 0; i < 8; i++)
#pragma unroll
    for (int j = 0; j < 4; j++) acc[i][j] = (f32x4){0.f, 0.f, 0.f, 0.f};

  const u16* ag = xbf + (size_t)(bm * 256) * D_IN;
  const u16* bg = wbf + (size_t)(bn * 256) * D_IN;

  // staging thread-constants (pre-swizzled global source offsets)
  const int aR0 = tid >> 3,         aG = tid & 7;   // A: row-in-half, granule
  const int aR1 = (tid + 512) >> 3;
  const int bR0 = tid >> 2,         bG = tid & 3;   // B: row, granule
  const int bR1 = (tid + 512) >> 2;
  const size_t aO0 = (size_t)aR0 * D_IN + (size_t)((aG ^ (aR0 & 7)) * 8);
  const size_t aO1 = (size_t)aR1 * D_IN + (size_t)((aG ^ (aR1 & 7)) * 8);
  const size_t bO0 = (size_t)bR0 * D_IN + (size_t)((bG ^ (bR0 & 3)) * 8);
  const size_t bO1 = (size_t)bR1 * D_IN + (size_t)((bG ^ (bR1 & 3)) * 8);
  const int wbase = w * 1024;

#define STAGE_A(BUF, H, K0) {                                         \
    char* l_ = smem + (BUF) * 32768 + (H) * 16384 + wbase;            \
    const u16* g_ = ag + (size_t)((H) * 128) * D_IN + (K0);           \
    gload_lds16(g_ + aO0, l_);                                        \
    gload_lds16(g_ + aO1, l_ + 8192); }
#define STAGE_B(BUF, KF, K0) {                                        \
    char* l_ = smem + 65536 + (BUF) * 32768 + (KF) * 16384 + wbase;   \
    const u16* g_ = bg + (size_t)(K0) + (KF) * 32;                    \
    gload_lds16(g_ + bO0, l_);                                        \
    gload_lds16(g_ + bO1, l_ + 8192); }

#define RD_A(BUF, KF, MI)                                                     \
  (*(const short8*)(smem + (BUF) * 32768 +                                    \
                    (wm * 128 + (MI) * 16 + l15) * 128 +                      \
                    ((((KF) * 4 + l4) ^ (lane & 7)) * 16)))
#define RD_B(BUF, KF, NI)                                                     \
  (*(const short8*)(smem + 65536 + (BUF) * 32768 + (KF) * 16384 +             \
                    (wn * 64 + (NI) * 16 + l15) * 64 +                        \
                    ((l4 ^ (lane & 3)) * 16)))

  // prologue: tile 0, issue order A0, Bkf0, A1, Bkf1; keep Bkf1 in flight
  STAGE_A(0, 0, 0); STAGE_B(0, 0, 0); STAGE_A(0, 1, 0); STAGE_B(0, 1, 0);
  asm volatile("s_waitcnt vmcnt(2)" ::: "memory");
  __syncthreads();

  short8 af[4], bfr[4];
  for (int T = 0; T < NT; ++T) {
    const int b  = T & 1;
    const int kN = ((T + 1) & (NT - 1)) * 64;   // wrap on last tile (uniform counts)

    // ---- P0: B(kf0) + A(kf0, mi0-3); stage A0 of T+1 ----
#pragma unroll
    for (int n = 0; n < 4; n++) bfr[n] = RD_B(b, 0, n);
#pragma unroll
    for (int i = 0; i < 4; i++) af[i] = RD_A(b, 0, i);
    STAGE_A(b ^ 1, 0, kN);
    __builtin_amdgcn_s_setprio(1);
    MFMA16(0)
    __builtin_amdgcn_s_setprio(0);
    __syncthreads();

    // ---- P1: A(kf0, mi4-7); stage Bkf0 of T+1; vmcnt(4) ----
#pragma unroll
    for (int i = 0; i < 4; i++) af[i] = RD_A(b, 0, 4 + i);
    STAGE_B(b ^ 1, 0, kN);
    __builtin_amdgcn_s_setprio(1);
    MFMA16(1)
    __builtin_amdgcn_s_setprio(0);
    asm volatile("s_waitcnt vmcnt(4)" ::: "memory");   // Bkf1(T) resident
    __syncthreads();

    // ---- P2: B(kf1) + A(kf1, mi0-3); stage A1 of T+1 ----
#pragma unroll
    for (int n = 0; n < 4; n++) bfr[n] = RD_B(b, 1, n);
#pragma unroll
    for (int i = 0; i < 4; i++) af[i] = RD_A(b, 1, i);
    STAGE_A(b ^ 1, 1, kN);
    __builtin_amdgcn_s_setprio(1);
    MFMA16(0)
    __builtin_amdgcn_s_setprio(0);
    __syncthreads();

    // ---- P3: A(kf1, mi4-7); stage Bkf1 of T+1; vmcnt(2) ----
#pragma unroll
    for (int i = 0; i < 4; i++) af[i] = RD_A(b, 1, 4 + i);
    STAGE_B(b ^ 1, 1, kN);
    __builtin_amdgcn_s_setprio(1);
    MFMA16(1)
    __builtin_amdgcn_s_setprio(0);
    asm volatile("s_waitcnt vmcnt(2)" ::: "memory");   // A0,Bkf0,A1 of T+1 resident
    __syncthreads();
  }

  // epilogue: C frag layout col=lane&15, row=(lane>>4)*4+reg
  const int colbase = bn * 256 + wn * 64 + l15;
  const int rowbase = bm * 256 + wm * 128 + l4 * 4;
#pragma unroll
  for (int ni = 0; ni < 4; ni++) {
    int col = colbase + ni * 16;
    float be = b_enc[col];
#pragma unroll
    for (int mi = 0; mi < 8; mi++) {
#pragma unroll
      for (int r = 0; r < 4; r++) {
        int row = rowbase + mi * 16 + r;
        float v = acc[mi][ni][r] + be;
        z[(size_t)row * WIDTH + col] = v > 0.f ? v : 0.f;
      }
    }
  }
}

// ========= K2a: per-row top-64 set selection (register-resident row) =========
__global__ __launch_bounds__(256) void sae_select2(
    float* __restrict__ z, const float* __restrict__ x,
    const float* __restrict__ W, const float* __restrict__ b_enc,
    float* __restrict__ xhat)
{
  __shared__ float  xrow[D_IN];
  __shared__ u32    hist[256];
  __shared__ int    ci[CAP];
  __shared__ float  cs[CAP];
  __shared__ int    ucand[CAP];
  __shared__ double uval[CAP];
  __shared__ u32    wflag[CAP];
  __shared__ int    si[TOPK];
  __shared__ float  sv[TOPK];
  __shared__ int    ncand_s, nunc_s, m_s, sel_hi_s;
  __shared__ u32    g1_s;
  __shared__ float  tp_s;

  const int tid = threadIdx.x;
  const int b   = blockIdx.x;
  float* zrow = z + (size_t)b * WIDTH;
  const float4* zr4 = (const float4*)zrow;

  for (int i = tid; i < D_IN / 4; i += 256)
    ((float4*)xrow)[i] = ((const float4*)(x + (size_t)b * D_IN))[i];
  if (tid == 0) { ncand_s = 0; nunc_s = 0; m_s = 0; }
  if (tid < TOPK) { si[tid] = 0; sv[tid] = 0.f; }
  hist[tid] = 0;
  __syncthreads();

  u32 pk[32];
#pragma unroll
  for (int i = 0; i < 16; i++) {
    float4 v = zr4[i * 256 + tid];
    pk[2 * i]     = rne16(v.x) | (rne16(v.y) << 16);
    pk[2 * i + 1] = rne16(v.z) | (rne16(v.w) << 16);
  }

#pragma unroll
  for (int i = 0; i < 32; i++) {
    u32 p = pk[i];
    atomicAdd(&hist[(p >> 8) & 255u], 1u);
    atomicAdd(&hist[p >> 24], 1u);
  }
  __syncthreads();
  if (tid == 0) {
    u32 cum = 0; int hi = 255;
    for (; hi > 0; hi--) { if (cum + hist[hi] >= TOPK) break; cum += hist[hi]; }
    sel_hi_s = hi; g1_s = cum;
  }
  __syncthreads();
  int sel_hi = sel_hi_s;
  hist[tid] = 0;
  __syncthreads();
#pragma unroll
  for (int i = 0; i < 32; i++) {
    u32 p = pk[i];
    if ((int)((p >> 8) & 255u) == sel_hi) atomicAdd(&hist[p & 255u], 1u);
    if ((int)(p >> 24) == sel_hi) atomicAdd(&hist[(p >> 16) & 255u], 1u);
  }
  __syncthreads();
  if (tid == 0) {
    u32 target = TOPK - g1_s;
    u32 cum = 0; int lo = 255;
    for (; lo > 0; lo--) { cum += hist[lo]; if (cum >= target) break; }
    tp_s = bf16f((u16)((sel_hi << 8) | lo));
  }
  __syncthreads();
  float tp = tp_s;
  float cLo = tp - COLL;

#pragma unroll
  for (int i = 0; i < 16; i++) {
    u32 p0 = pk[2 * i], p1 = pk[2 * i + 1];
    int j0 = (i * 256 + tid) * 4;
    if (bf16f((u16)p0) >= cLo)         { int p = atomicAdd(&ncand_s, 1); if (p < CAP) ci[p] = j0; }
    if (bf16f((u16)(p0 >> 16)) >= cLo) { int p = atomicAdd(&ncand_s, 1); if (p < CAP) ci[p] = j0 + 1; }
    if (bf16f((u16)p1) >= cLo)         { int p = atomicAdd(&ncand_s, 1); if (p < CAP) ci[p] = j0 + 2; }
    if (bf16f((u16)(p1 >> 16)) >= cLo) { int p = atomicAdd(&ncand_s, 1); if (p < CAP) ci[p] = j0 + 3; }
  }
  __syncthreads();
  int nc = ncand_s; if (nc > CAP) nc = CAP;

  for (int c = tid; c < nc; c += 256) {
    float s = zrow[ci[c]];
    cs[c] = s;
    if (s > tp + SURE) { atomicAdd(&m_s, 1); wflag[c] = 1u; }
    else {
      wflag[c] = 0u;
      if (s >= tp - SURE) { int q = atomicAdd(&nunc_s, 1); ucand[q] = c; }
    }
  }
  __syncthreads();
  int m = m_s, nu = nunc_s;
  int k_rem = TOPK - m;

  int wv = tid >> 6, lane = tid & 63;
  for (int q = wv; q < nu; q += 4) {
    int jc = ci[ucand[q]];
    const float4* wr = (const float4*)(W + (size_t)jc * D_IN);
    double s = 0.0;
    for (int it = 0; it < D_IN / 4 / 64; it++) {
      float4 wd = wr[it * 64 + lane];
      int d = (it * 64 + lane) * 4;
      s += (double)xrow[d + 0] * (double)wd.x;
      s += (double)xrow[d + 1] * (double)wd.y;
      s += (double)xrow[d + 2] * (double)wd.z;
      s += (double)xrow[d + 3] * (double)wd.w;
    }
    for (int off = 32; off >= 1; off >>= 1) s += __shfl_down(s, off, 64);
    if (lane == 0) {
      double v = s + (double)b_enc[jc];
      uval[q] = v > 0.0 ? v : 0.0;
    }
  }
  __syncthreads();

  for (int q = tid; q < nu; q += 256) {
    double v = uval[q]; int jq = ci[ucand[q]];
    int rank = 0;
    for (int p = 0; p < nu; p++) {
      double vp = uval[p];
      if (vp > v || (vp == v && ci[ucand[p]] < jq)) rank++;
    }
    if (rank < k_rem) wflag[ucand[q]] = 1u;
  }
  __syncthreads();

  for (int c = tid; c < nc; c += 256) {
    if (wflag[c]) {
      int jme = ci[c];
      int slot = 0;
      for (int p = 0; p < nc; p++) slot += (wflag[p] && ci[p] < jme) ? 1 : 0;
      si[slot] = jme;
      sv[slot] = cs[c];
    }
  }
  __syncthreads();

  for (int i = tid; i < WIDTH / 4; i += 256)
    *(float4*)(zrow + i * 4) = make_float4(0.f, 0.f, 0.f, 0.f);
  __syncthreads();
  if (tid < TOPK) zrow[si[tid]] = sv[tid];

  u32* lidx = (u32*)(xhat + (size_t)b * D_IN);
  if (tid < TOPK) {
    lidx[tid] = (u32)si[tid];
    ((float*)lidx)[TOPK + tid] = sv[tid];
  }
}

// ========= K2b: sparse decode from bf16 W =========
__global__ __launch_bounds__(256) void sae_decode2(
    const u16* __restrict__ wbf, const float* __restrict__ b_dec,
    float* __restrict__ xhat)
{
  __shared__ int   si[TOPK];
  __shared__ float sv[TOPK];
  const int tid = threadIdx.x;
  const int b   = blockIdx.x;
  float* xo = xhat + (size_t)b * D_IN;

  if (tid < TOPK) {
    si[tid] = (int)((const u32*)xo)[tid];
    sv[tid] = xo[TOPK + tid];
  }
  __syncthreads();

  float a[8];
#pragma unroll
  for (int u = 0; u < 8; u++) a[u] = 0.f;
  for (int k = 0; k < TOPK; k++) {
    int j = si[k]; float v = sv[k];
    uint4 wv = *(const uint4*)(wbf + (size_t)j * D_IN + tid * 8);
    a[0] = fmaf(v, __uint_as_float(wv.x << 16),         a[0]);
    a[1] = fmaf(v, __uint_as_float(wv.x & 0xFFFF0000u), a[1]);
    a[2] = fmaf(v, __uint_as_float(wv.y << 16),         a[2]);
    a[3] = fmaf(v, __uint_as_float(wv.y & 0xFFFF0000u), a[3]);
    a[4] = fmaf(v, __uint_as_float(wv.z << 16),         a[4]);
    a[5] = fmaf(v, __uint_as_float(wv.z & 0xFFFF0000u), a[5]);
    a[6] = fmaf(v, __uint_as_float(wv.w << 16),         a[6]);
    a[7] = fmaf(v, __uint_as_float(wv.w & 0xFFFF0000u), a[7]);
  }
  int d0 = tid * 8;
  float4 bd0 = *(const float4*)(b_dec + d0);
  float4 bd1 = *(const float4*)(b_dec + d0 + 4);
  __syncthreads();
  *(float4*)(xo + d0)     = make_float4(a[0] + bd0.x, a[1] + bd0.y, a[2] + bd0.z, a[3] + bd0.w);
  *(float4*)(xo + d0 + 4) = make_float4(a[4] + bd1.x, a[5] + bd1.y, a[6] + bd1.z, a[7] + bd1.w);
}

// ------------------------------- launch -------------------------------
extern "C" void kernel_launch(void* const* d_in, const int* in_sizes, int n_in,
                              void* d_out, int out_size, void* d_ws, size_t ws_size,
                              hipStream_t stream) {
  const float* x     = (const float*)d_in[0];
  const float* W     = (const float*)d_in[1];
  const float* b_enc = (const float*)d_in[2];
  const float* b_dec = (const float*)d_in[3];
  (void)in_sizes; (void)n_in; (void)out_size; (void)ws_size;

  float* z_out = (float*)d_out;                      // [BATCH][WIDTH] f32
  float* xhat  = z_out + (size_t)BATCH * WIDTH;      // [BATCH][D_IN] f32

  u16* xbf = (u16*)d_ws;                             // 33.5 MB
  u16* wbf = xbf + (size_t)BATCH * D_IN;             // 67.1 MB

  cvt_bf16_k<<<2048, 256, 0, stream>>>(x, xbf, BATCH * D_IN / 4);
  cvt_bf16_k<<<2048, 256, 0, stream>>>(W, wbf, WIDTH * D_IN / 4);

  dim3 g1(WIDTH / 256, BATCH / 256);                 // 64 x 32, bn fast
  sae_enc_8ph<<<g1, 512, 0, stream>>>(xbf, wbf, b_enc, z_out);
  sae_select2<<<BATCH, 256, 0, stream>>>(z_out, x, W, b_enc, xhat);
  sae_decode2<<<BATCH, 256, 0, stream>>>(wbf, b_dec, xhat);
}